// Round 13
// baseline (402.251 us; speedup 1.0000x reference)
//
#include <hip/hip_runtime.h>
#include <hip/hip_fp16.h>
#include <math.h>

#define NEG_SLOPE 0.2f
#define BUCKET 96            // fixed bucket stride (slots per node); P(deg>95) ~ 1e-28

__device__ __forceinline__ float lrelu(float x) { return fmaxf(x, NEG_SLOPE * x); }

// One DPP cross-lane add step (VALU pipe, no DS ops). ctrl must be compile-time.
template <int CTRL>
__device__ __forceinline__ float dpp_add(float x) {
    int t = __builtin_amdgcn_update_dpp(0, __float_as_int(x), CTRL, 0xF, 0xF, false);
    return x + __int_as_float(t);
}

// Sum over each 8-lane group (values replicated in group).
__device__ __forceinline__ float red8(float x) {
    x = dpp_add<0xB1>(x);    // quad_perm [1,0,3,2]  (xor 1)
    x = dpp_add<0x4E>(x);    // quad_perm [2,3,0,1]  (xor 2)
    x = dpp_add<0x141>(x);   // row_half_mirror      (xor 4, quads uniform)
    return x;
}

// Sum over each 32-lane half (values replicated in half).
__device__ __forceinline__ float red32(float x) {
    x = red8(x);
    x = dpp_add<0x140>(x);           // row_mirror (xor 8, 8-groups uniform)
    x += __shfl_xor(x, 16, 64);      // xor 16 (stays within each 32-half)
    return x;
}

// ---- CSR build, one pass: dst-range-partitioned direct scatter into fixed buckets.
// partition == blockIdx%8 == XCD (round-robin) -> each partition's 2.4 MB write
// region stays in one XCD's L2; src read only for in-range edges.
__global__ void k_scatter(const int* __restrict__ ei, int* __restrict__ cnt,
                          int* __restrict__ ssrc, int E, int ET, int n, int nsub) {
    int part = blockIdx.x & 7;
    int sub  = blockIdx.x >> 3;
    int lo = (int)(((long long)part * n) >> 3);
    int hi = (int)(((long long)(part + 1) * n) >> 3);
    int stride = nsub * blockDim.x;
    for (int e = sub * blockDim.x + threadIdx.x; e < ET; e += stride) {
        int dst = (e < E) ? ei[E + e] : (e - E);
        if (dst >= lo && dst < hi) {
            int src = (e < E) ? ei[e] : dst;
            int pos = atomicAdd(&cnt[dst], 1);
            if (pos < BUCKET) ssrc[dst * BUCKET + pos] = src;
        }
    }
}

// ---- Layer-1 node transform: xl1 = x@W1l (fp16), xr1 = x@W1r (fp32) ----
__global__ void k_t1(const float* __restrict__ x,
                     const float* __restrict__ W1l, const float* __restrict__ W1r,
                     __half* __restrict__ xl, float* __restrict__ xr, int n) {
    __shared__ float sWl[5 * 64], sWr[5 * 64];
    int t = threadIdx.x;
    for (int i = t; i < 5 * 64; i += blockDim.x) { sWl[i] = W1l[i]; sWr[i] = W1r[i]; }
    __syncthreads();
    int tid = blockIdx.x * blockDim.x + t;
    if (tid >= n * 64) return;
    int node = tid >> 6, j = tid & 63;
    const float* xp = x + node * 5;
    float x0 = xp[0], x1 = xp[1], x2 = xp[2], x3 = xp[3], x4 = xp[4];
    float al = x0 * sWl[j] + x1 * sWl[64 + j] + x2 * sWl[128 + j] + x3 * sWl[192 + j] + x4 * sWl[256 + j];
    float ar = x0 * sWr[j] + x1 * sWr[64 + j] + x2 * sWr[128 + j] + x3 * sWr[192 + j] + x4 * sWr[256 + j];
    xl[tid] = __float2half(al);
    xr[tid] = ar;
}

// ---- Layer 1 fused GATv2: wave per node, 2 edges/wave (32 lanes x 2 dims),
//      16-edge main loop with SOFTWARE-PIPELINED scalar index prefetch
//      (next batch's 16 bucket indices preloaded into SGPRs during current batch).
//      Head logit = 8-lane DPP reduce. Epilogue: h1 -> LDS -> layer-2 transform.
__global__ void __launch_bounds__(256, 8)
k_gat1(const int* __restrict__ ssrc, const int* __restrict__ deg,
       const __half* __restrict__ xl, const float* __restrict__ xr,
       const float* __restrict__ att1, const float* __restrict__ b1,
       const float* __restrict__ W2l, const float* __restrict__ W2r,
       __half* __restrict__ hl, float* __restrict__ hr, int n) {
    __shared__ float sh[4][64];
    int t = threadIdx.x;
    int wid = t >> 6, lane = t & 63;
    int node = __builtin_amdgcn_readfirstlane(blockIdx.x * 4 + wid);
    int half = lane >> 5, l31 = lane & 31;
    if (node < n) {
        float2 xrd  = *(const float2*)(xr + (size_t)node * 64 + 2 * l31);
        float2 attv = *(const float2*)(att1 + 2 * l31);
        float m = -INFINITY, den = 0.f, acc0 = 0.f, acc1 = 0.f;
        const int* bp_ = ssrc + (size_t)node * BUCKET;    // bucket base (node uniform)
        int end = deg[node]; if (end > BUCKET) end = BUCKET;
        int k = 0;
        if (end >= 16) {
            int idx[16];
#pragma unroll
            for (int j = 0; j < 16; ++j) idx[j] = bp_[j];
            while (k + 15 < end) {
                int idxn[16];
#pragma unroll
                for (int j = 0; j < 16; ++j) idxn[j] = bp_[k + 16 + j];  // prefetch (slack-safe)
                float2 a[8];
#pragma unroll
                for (int j = 0; j < 8; ++j) {
                    int sj = half ? idx[2 * j + 1] : idx[2 * j];
                    a[j] = __half22float2(*(const __half2*)(xl + ((unsigned)sj << 6) + 2u * l31));
                }
                float s[8];
#pragma unroll
                for (int j = 0; j < 8; ++j)
                    s[j] = lrelu(a[j].x + xrd.x) * attv.x + lrelu(a[j].y + xrd.y) * attv.y;
#pragma unroll
                for (int j = 0; j < 8; ++j) s[j] = red8(s[j]);
                float mb = fmaxf(fmaxf(fmaxf(s[0], s[1]), fmaxf(s[2], s[3])),
                                 fmaxf(fmaxf(s[4], s[5]), fmaxf(s[6], s[7])));
                float mn = fmaxf(m, mb);
                float sc = __expf(m - mn);
                den *= sc; acc0 *= sc; acc1 *= sc;
#pragma unroll
                for (int j = 0; j < 8; ++j) {
                    float p = __expf(s[j] - mn);
                    den += p; acc0 += p * a[j].x; acc1 += p * a[j].y;
                }
                m = mn;
#pragma unroll
                for (int j = 0; j < 16; ++j) idx[j] = idxn[j];
                k += 16;
            }
        }
        for (; k + 7 < end; k += 8) {                     // 8-edge tier
            float2 a[4];
#pragma unroll
            for (int j = 0; j < 4; ++j) {
                int s0 = bp_[k + 2 * j], s1 = bp_[k + 2 * j + 1];
                int sj = half ? s1 : s0;
                a[j] = __half22float2(*(const __half2*)(xl + ((unsigned)sj << 6) + 2u * l31));
            }
            float s[4];
#pragma unroll
            for (int j = 0; j < 4; ++j)
                s[j] = lrelu(a[j].x + xrd.x) * attv.x + lrelu(a[j].y + xrd.y) * attv.y;
#pragma unroll
            for (int j = 0; j < 4; ++j) s[j] = red8(s[j]);
            float mb = fmaxf(fmaxf(s[0], s[1]), fmaxf(s[2], s[3]));
            float mn = fmaxf(m, mb);
            float sc = __expf(m - mn);
            den *= sc; acc0 *= sc; acc1 *= sc;
#pragma unroll
            for (int j = 0; j < 4; ++j) {
                float p = __expf(s[j] - mn);
                den += p; acc0 += p * a[j].x; acc1 += p * a[j].y;
            }
            m = mn;
        }
        for (; k + 1 < end; k += 2) {
            int s0 = bp_[k], s1 = bp_[k + 1];
            int sj = half ? s1 : s0;
            float2 a = __half22float2(*(const __half2*)(xl + ((unsigned)sj << 6) + 2u * l31));
            float s = lrelu(a.x + xrd.x) * attv.x + lrelu(a.y + xrd.y) * attv.y;
            s = red8(s);
            float mn = fmaxf(m, s);
            float sc = __expf(m - mn);
            float p  = __expf(s - mn);
            den = den * sc + p;
            acc0 = acc0 * sc + p * a.x;
            acc1 = acc1 * sc + p * a.y;
            m = mn;
        }
        if (k < end) {                                    // odd tail: lo half only
            int sj = bp_[k];
            float2 a = __half22float2(*(const __half2*)(xl + ((unsigned)sj << 6) + 2u * l31));
            float s = lrelu(a.x + xrd.x) * attv.x + lrelu(a.y + xrd.y) * attv.y;
            s = red8(s);
            if (half == 0) {
                float mn = fmaxf(m, s);
                float sc = __expf(m - mn);
                float p  = __expf(s - mn);
                den = den * sc + p;
                acc0 = acc0 * sc + p * a.x;
                acc1 = acc1 * sc + p * a.y;
                m = mn;
            }
        }
        // merge halves (lo half has >=1 edge so no double -inf)
        float m_o  = __shfl_xor(m, 32, 64);
        float d_o  = __shfl_xor(den, 32, 64);
        float a0_o = __shfl_xor(acc0, 32, 64);
        float a1_o = __shfl_xor(acc1, 32, 64);
        float mf = fmaxf(m, m_o);
        float sc = __expf(m - mf), sco = __expf(m_o - mf);
        float denf = den * sc + d_o * sco + 1e-16f;
        float2 b = *(const float2*)(b1 + 2 * l31);
        float o0 = fmaxf((acc0 * sc + a0_o * sco) / denf + b.x, 0.f);
        float o1 = fmaxf((acc1 * sc + a1_o * sco) / denf + b.y, 0.f);
        if (half == 0) *(float2*)&sh[wid][2 * l31] = make_float2(o0, o1);
    }
    __syncthreads();
    if (node >= n) return;
    // ---- layer-2 transform: hl = h1@W2l (fp16), hr = h1@W2r (fp32), dim = lane ----
    float accl = 0.f, accr = 0.f;
#pragma unroll 8
    for (int q = 0; q < 64; ++q) {
        float hv = sh[wid][q];
        accl += hv * W2l[q * 64 + lane];
        accr += hv * W2r[q * 64 + lane];
    }
    hl[(size_t)node * 64 + lane] = __float2half(accl);
    hr[(size_t)node * 64 + lane] = accr;
}

// ---- Layer 2 fused GATv2 + pool: wave per node, 2 edges/wave,
//      16-edge main loop with pipelined scalar index prefetch.
__global__ void __launch_bounds__(256, 8)
k_gat2(const int* __restrict__ ssrc, const int* __restrict__ deg,
       const __half* __restrict__ hl, const float* __restrict__ hr,
       const float* __restrict__ att2, const float* __restrict__ b2,
       const int* __restrict__ batch,
       float* __restrict__ pooled, float* __restrict__ cnt, int n) {
    int node = __builtin_amdgcn_readfirstlane((blockIdx.x * blockDim.x + threadIdx.x) >> 6);
    if (node >= n) return;
    int lane = threadIdx.x & 63;
    int half = lane >> 5, l31 = lane & 31;
    float2 hrd  = *(const float2*)(hr + (size_t)node * 64 + 2 * l31);
    float2 attv = *(const float2*)(att2 + 2 * l31);
    float m = -INFINITY, den = 0.f, acc0 = 0.f, acc1 = 0.f;
    const int* bp_ = ssrc + (size_t)node * BUCKET;
    int end = deg[node]; if (end > BUCKET) end = BUCKET;
    int k = 0;
    if (end >= 16) {
        int idx[16];
#pragma unroll
        for (int j = 0; j < 16; ++j) idx[j] = bp_[j];
        while (k + 15 < end) {
            int idxn[16];
#pragma unroll
            for (int j = 0; j < 16; ++j) idxn[j] = bp_[k + 16 + j];  // prefetch (slack-safe)
            float2 a[8];
#pragma unroll
            for (int j = 0; j < 8; ++j) {
                int sj = half ? idx[2 * j + 1] : idx[2 * j];
                a[j] = __half22float2(*(const __half2*)(hl + ((unsigned)sj << 6) + 2u * l31));
            }
            float s[8];
#pragma unroll
            for (int j = 0; j < 8; ++j)
                s[j] = lrelu(a[j].x + hrd.x) * attv.x + lrelu(a[j].y + hrd.y) * attv.y;
#pragma unroll
            for (int j = 0; j < 8; ++j) s[j] = red32(s[j]);
            float mb = fmaxf(fmaxf(fmaxf(s[0], s[1]), fmaxf(s[2], s[3])),
                             fmaxf(fmaxf(s[4], s[5]), fmaxf(s[6], s[7])));
            float mn = fmaxf(m, mb);
            float sc = __expf(m - mn);
            den *= sc; acc0 *= sc; acc1 *= sc;
#pragma unroll
            for (int j = 0; j < 8; ++j) {
                float p = __expf(s[j] - mn);
                den += p; acc0 += p * a[j].x; acc1 += p * a[j].y;
            }
            m = mn;
#pragma unroll
            for (int j = 0; j < 16; ++j) idx[j] = idxn[j];
            k += 16;
        }
    }
    for (; k + 7 < end; k += 8) {                         // 8-edge tier
        float2 a[4];
#pragma unroll
        for (int j = 0; j < 4; ++j) {
            int s0 = bp_[k + 2 * j], s1 = bp_[k + 2 * j + 1];
            int sj = half ? s1 : s0;
            a[j] = __half22float2(*(const __half2*)(hl + ((unsigned)sj << 6) + 2u * l31));
        }
        float s[4];
#pragma unroll
        for (int j = 0; j < 4; ++j)
            s[j] = lrelu(a[j].x + hrd.x) * attv.x + lrelu(a[j].y + hrd.y) * attv.y;
#pragma unroll
        for (int j = 0; j < 4; ++j) s[j] = red32(s[j]);
        float mb = fmaxf(fmaxf(s[0], s[1]), fmaxf(s[2], s[3]));
        float mn = fmaxf(m, mb);
        float sc = __expf(m - mn);
        den *= sc; acc0 *= sc; acc1 *= sc;
#pragma unroll
        for (int j = 0; j < 4; ++j) {
            float p = __expf(s[j] - mn);
            den += p; acc0 += p * a[j].x; acc1 += p * a[j].y;
        }
        m = mn;
    }
    for (; k + 1 < end; k += 2) {
        int s0 = bp_[k], s1 = bp_[k + 1];
        int sj = half ? s1 : s0;
        float2 a = __half22float2(*(const __half2*)(hl + ((unsigned)sj << 6) + 2u * l31));
        float s = lrelu(a.x + hrd.x) * attv.x + lrelu(a.y + hrd.y) * attv.y;
        s = red32(s);
        float mn = fmaxf(m, s);
        float sc = __expf(m - mn);
        float p  = __expf(s - mn);
        den = den * sc + p;
        acc0 = acc0 * sc + p * a.x;
        acc1 = acc1 * sc + p * a.y;
        m = mn;
    }
    if (k < end) {                                        // odd tail: lo half only
        int sj = bp_[k];
        float2 a = __half22float2(*(const __half2*)(hl + ((unsigned)sj << 6) + 2u * l31));
        float s = lrelu(a.x + hrd.x) * attv.x + lrelu(a.y + hrd.y) * attv.y;
        s = red32(s);
        if (half == 0) {
            float mn = fmaxf(m, s);
            float sc = __expf(m - mn);
            float p  = __expf(s - mn);
            den = den * sc + p;
            acc0 = acc0 * sc + p * a.x;
            acc1 = acc1 * sc + p * a.y;
            m = mn;
        }
    }
    // merge halves
    float m_o  = __shfl_xor(m, 32, 64);
    float d_o  = __shfl_xor(den, 32, 64);
    float a0_o = __shfl_xor(acc0, 32, 64);
    float a1_o = __shfl_xor(acc1, 32, 64);
    float mf = fmaxf(m, m_o);
    float sc = __expf(m - mf), sco = __expf(m_o - mf);
    float denf = den * sc + d_o * sco + 1e-16f;
    float2 b = *(const float2*)(b2 + 2 * l31);
    float o0 = fmaxf((acc0 * sc + a0_o * sco) / denf + b.x, 0.f);
    float o1 = fmaxf((acc1 * sc + a1_o * sco) / denf + b.y, 0.f);
    // ---- pool epilogue: lane writes dim 2*l31+half (each dim exactly once) ----
    int g = batch[node];
    atomicAdd(&pooled[(size_t)g * 64 + 2 * l31 + half], half ? o1 : o0);
    if (lane == 0) atomicAdd(&cnt[g], 1.0f);
}

// ---- Predict: out[g] = dot(pooled[g]/max(cnt,1), Wp) + bp ----
__global__ void k_predict(const float* __restrict__ pooled, const float* __restrict__ cnt,
                          const float* __restrict__ Wp, const float* __restrict__ bp,
                          float* __restrict__ out, int G) {
    int tid = blockIdx.x * blockDim.x + threadIdx.x;
    int g = tid >> 6;
    if (g >= G) return;
    int lane = threadIdx.x & 63;
    float c = cnt[g];
    if (c < 1.f) c = 1.f;
    float v = (pooled[(size_t)g * 64 + lane] / c) * Wp[lane];
#pragma unroll
    for (int off = 32; off > 0; off >>= 1) v += __shfl_down(v, off, 64);
    if (lane == 0) out[g] = v + bp[0];
}

extern "C" void kernel_launch(void* const* d_in, const int* in_sizes, int n_in,
                              void* d_out, int out_size, void* d_ws, size_t ws_size,
                              hipStream_t stream) {
    const float* x    = (const float*)d_in[0];
    const int*   ei   = (const int*)d_in[1];
    const int*   batch= (const int*)d_in[2];
    const float* W1l  = (const float*)d_in[3];
    const float* W1r  = (const float*)d_in[4];
    const float* att1 = (const float*)d_in[5];
    const float* b1   = (const float*)d_in[6];
    const float* W2l  = (const float*)d_in[7];
    const float* W2r  = (const float*)d_in[8];
    const float* att2 = (const float*)d_in[9];
    const float* b2   = (const float*)d_in[10];
    const float* Wp   = (const float*)d_in[11];
    const float* bp   = (const float*)d_in[12];
    float* out = (float*)d_out;

    const int n  = in_sizes[0] / 5;        // 50000
    const int E  = in_sizes[1] / 2;        // 1600000
    const int ET = E + n;                  // +self-loops
    const int G  = out_size;               // 512

    // ---- workspace layout ----
    char* ws = (char*)d_ws;
    size_t off = 0;
    auto alloc_b = [&](size_t bytes) { void* p = (void*)(ws + off); off += (bytes + 15) & ~15ull; return p; };
    __half* xl    = (__half*)alloc_b((size_t)n * 64 * 2);  // layer-1 gather array (fp16)
    float*  xr    = (float*)alloc_b((size_t)n * 64 * 4);
    __half* hl    = (__half*)alloc_b((size_t)n * 64 * 2);  // layer-2 gather array (fp16)
    float*  hr    = (float*)alloc_b((size_t)n * 64 * 4);
    float*  pooled= (float*)alloc_b((size_t)G * 64 * 4);   // zero region start
    float*  cntf  = (float*)alloc_b((size_t)G * 4);
    int*    deg   = (int*)alloc_b((size_t)n * 4);          // zero region end
    int*    ssrc  = (int*)alloc_b((size_t)n * BUCKET * 4 + 64); // buckets (+16-int prefetch slack)

    size_t zero_bytes = (size_t)((char*)deg - (char*)pooled) + (size_t)n * 4;
    (void)hipMemsetAsync(pooled, 0, zero_bytes, stream);

    const int B = 256;
    const int NSUB = 256;                  // edge-chunks per dst-partition

    // one-pass CSR build into fixed buckets (deg[] = degrees as byproduct)
    k_scatter<<<8 * NSUB, B, 0, stream>>>(ei, deg, ssrc, E, ET, n, NSUB);

    // layer-1 node transform (independent of buckets)
    k_t1<<<(n * 64 + B - 1) / B, B, 0, stream>>>(x, W1l, W1r, xl, xr, n);

    // fused GAT layer 1 + transform2  ->  hl (fp16), hr (fp32)
    k_gat1<<<(n + 3) / 4, B, 0, stream>>>(ssrc, deg, xl, xr, att1, b1, W2l, W2r, hl, hr, n);
    // fused GAT layer 2 + pool
    k_gat2<<<((size_t)n * 64 + B - 1) / B, B, 0, stream>>>(ssrc, deg, hl, hr, att2, b2, batch, pooled, cntf, n);
    // predict
    k_predict<<<(G * 64 + B - 1) / B, B, 0, stream>>>(pooled, cntf, Wp, bp, out, G);
}

// Round 14
// 370.843 us; speedup vs baseline: 1.0847x; 1.0847x over previous
//
#include <hip/hip_runtime.h>
#include <hip/hip_fp16.h>
#include <math.h>

#define NEG_SLOPE 0.2f
#define BUCKET 96            // fixed bucket stride (slots per node); P(deg>95) ~ 1e-28
#define SC_NSUB 256          // edge-chunks per dst-partition (scatter half of k_build)

__device__ __forceinline__ float lrelu(float x) { return fmaxf(x, NEG_SLOPE * x); }

// One DPP cross-lane add step (VALU pipe, no DS ops). ctrl must be compile-time.
template <int CTRL>
__device__ __forceinline__ float dpp_add(float x) {
    int t = __builtin_amdgcn_update_dpp(0, __float_as_int(x), CTRL, 0xF, 0xF, false);
    return x + __int_as_float(t);
}

// Sum over each 8-lane group (values replicated in group).
__device__ __forceinline__ float red8(float x) {
    x = dpp_add<0xB1>(x);    // quad_perm [1,0,3,2]  (xor 1)
    x = dpp_add<0x4E>(x);    // quad_perm [2,3,0,1]  (xor 2)
    x = dpp_add<0x141>(x);   // row_half_mirror      (xor 4, quads uniform)
    return x;
}

// Sum over each 32-lane half (values replicated in half).
__device__ __forceinline__ float red32(float x) {
    x = red8(x);
    x = dpp_add<0x140>(x);           // row_mirror (xor 8, 8-groups uniform)
    x += __shfl_xor(x, 16, 64);      // xor 16 (stays within each 32-half)
    return x;
}

// ---- Fused build: blocks [0, 8*SC_NSUB) run the dst-partitioned bucket scatter;
//      remaining blocks run the layer-1 node transform. Branch is block-uniform,
//      so the t1-path __syncthreads is safe. The two halves are independent and
//      overlap on the machine instead of serializing on the stream.
__global__ void k_build(const int* __restrict__ ei, int* __restrict__ cnt,
                        int* __restrict__ ssrc, int E, int ET, int n,
                        const float* __restrict__ x,
                        const float* __restrict__ W1l, const float* __restrict__ W1r,
                        __half* __restrict__ xl, float* __restrict__ xr) {
    if (blockIdx.x < 8 * SC_NSUB) {
        // ---- scatter half: partition (blockIdx%8) owns 1/8 dst range (XCD-local
        //      if round-robin holds); src read only for in-range edges ----
        int part = blockIdx.x & 7;
        int sub  = blockIdx.x >> 3;
        int lo = (int)(((long long)part * n) >> 3);
        int hi = (int)(((long long)(part + 1) * n) >> 3);
        int stride = SC_NSUB * blockDim.x;
        for (int e = sub * blockDim.x + threadIdx.x; e < ET; e += stride) {
            int dst = (e < E) ? ei[E + e] : (e - E);
            if (dst >= lo && dst < hi) {
                int src = (e < E) ? ei[e] : dst;
                int pos = atomicAdd(&cnt[dst], 1);
                if (pos < BUCKET) ssrc[dst * BUCKET + pos] = src;
            }
        }
    } else {
        // ---- t1 half: xl = x@W1l (fp16), xr = x@W1r (fp32) ----
        __shared__ float sWl[5 * 64], sWr[5 * 64];
        int t = threadIdx.x;
        for (int i = t; i < 5 * 64; i += blockDim.x) { sWl[i] = W1l[i]; sWr[i] = W1r[i]; }
        __syncthreads();
        int tid = (blockIdx.x - 8 * SC_NSUB) * blockDim.x + t;
        if (tid >= n * 64) return;
        int node = tid >> 6, j = tid & 63;
        const float* xp = x + node * 5;
        float x0 = xp[0], x1 = xp[1], x2 = xp[2], x3 = xp[3], x4 = xp[4];
        float al = x0 * sWl[j] + x1 * sWl[64 + j] + x2 * sWl[128 + j] + x3 * sWl[192 + j] + x4 * sWl[256 + j];
        float ar = x0 * sWr[j] + x1 * sWr[64 + j] + x2 * sWr[128 + j] + x3 * sWr[192 + j] + x4 * sWr[256 + j];
        xl[tid] = __float2half(al);
        xr[tid] = ar;
    }
}

// ---- Layer 1 fused GATv2 (R10 config): wave per node, 2 edges/wave (32 lanes x 2 dims),
//      unrolled x8 (16 edges, 8 gathers/lane in flight). Head logit = 8-lane DPP.
//      Epilogue: h1 -> LDS -> layer-2 transform (hl fp16, hr fp32).
__global__ void __launch_bounds__(256, 8)
k_gat1(const int* __restrict__ ssrc, const int* __restrict__ deg,
       const __half* __restrict__ xl, const float* __restrict__ xr,
       const float* __restrict__ att1, const float* __restrict__ b1,
       const float* __restrict__ W2l, const float* __restrict__ W2r,
       __half* __restrict__ hl, float* __restrict__ hr, int n) {
    __shared__ float sh[4][64];
    int t = threadIdx.x;
    int wid = t >> 6, lane = t & 63;
    int node = __builtin_amdgcn_readfirstlane(blockIdx.x * 4 + wid);
    int half = lane >> 5, l31 = lane & 31;
    if (node < n) {
        float2 xrd  = *(const float2*)(xr + (size_t)node * 64 + 2 * l31);
        float2 attv = *(const float2*)(att1 + 2 * l31);
        float m = -INFINITY, den = 0.f, acc0 = 0.f, acc1 = 0.f;
        const int* bp_ = ssrc + (size_t)node * BUCKET;    // bucket base (node uniform)
        int end = deg[node]; if (end > BUCKET) end = BUCKET;
        int k = 0;
        for (; k + 15 < end; k += 16) {                   // 16 edges: 8 gathers in flight
            float2 a[8];
#pragma unroll
            for (int j = 0; j < 8; ++j) {
                int s0 = bp_[k + 2 * j], s1 = bp_[k + 2 * j + 1];
                int sj = half ? s1 : s0;
                a[j] = __half22float2(*(const __half2*)(xl + ((unsigned)sj << 6) + 2u * l31));
            }
            float s[8];
#pragma unroll
            for (int j = 0; j < 8; ++j)
                s[j] = lrelu(a[j].x + xrd.x) * attv.x + lrelu(a[j].y + xrd.y) * attv.y;
#pragma unroll
            for (int j = 0; j < 8; ++j) s[j] = red8(s[j]);
            float mb = fmaxf(fmaxf(fmaxf(s[0], s[1]), fmaxf(s[2], s[3])),
                             fmaxf(fmaxf(s[4], s[5]), fmaxf(s[6], s[7])));
            float mn = fmaxf(m, mb);
            float sc = __expf(m - mn);
            den *= sc; acc0 *= sc; acc1 *= sc;
#pragma unroll
            for (int j = 0; j < 8; ++j) {
                float p = __expf(s[j] - mn);
                den += p; acc0 += p * a[j].x; acc1 += p * a[j].y;
            }
            m = mn;
        }
        for (; k + 7 < end; k += 8) {                     // 8-edge tier
            float2 a[4];
#pragma unroll
            for (int j = 0; j < 4; ++j) {
                int s0 = bp_[k + 2 * j], s1 = bp_[k + 2 * j + 1];
                int sj = half ? s1 : s0;
                a[j] = __half22float2(*(const __half2*)(xl + ((unsigned)sj << 6) + 2u * l31));
            }
            float s[4];
#pragma unroll
            for (int j = 0; j < 4; ++j)
                s[j] = lrelu(a[j].x + xrd.x) * attv.x + lrelu(a[j].y + xrd.y) * attv.y;
#pragma unroll
            for (int j = 0; j < 4; ++j) s[j] = red8(s[j]);
            float mb = fmaxf(fmaxf(s[0], s[1]), fmaxf(s[2], s[3]));
            float mn = fmaxf(m, mb);
            float sc = __expf(m - mn);
            den *= sc; acc0 *= sc; acc1 *= sc;
#pragma unroll
            for (int j = 0; j < 4; ++j) {
                float p = __expf(s[j] - mn);
                den += p; acc0 += p * a[j].x; acc1 += p * a[j].y;
            }
            m = mn;
        }
        for (; k + 1 < end; k += 2) {
            int s0 = bp_[k], s1 = bp_[k + 1];
            int sj = half ? s1 : s0;
            float2 a = __half22float2(*(const __half2*)(xl + ((unsigned)sj << 6) + 2u * l31));
            float s = lrelu(a.x + xrd.x) * attv.x + lrelu(a.y + xrd.y) * attv.y;
            s = red8(s);
            float mn = fmaxf(m, s);
            float sc = __expf(m - mn);
            float p  = __expf(s - mn);
            den = den * sc + p;
            acc0 = acc0 * sc + p * a.x;
            acc1 = acc1 * sc + p * a.y;
            m = mn;
        }
        if (k < end) {                                    // odd tail: lo half only
            int sj = bp_[k];
            float2 a = __half22float2(*(const __half2*)(xl + ((unsigned)sj << 6) + 2u * l31));
            float s = lrelu(a.x + xrd.x) * attv.x + lrelu(a.y + xrd.y) * attv.y;
            s = red8(s);
            if (half == 0) {
                float mn = fmaxf(m, s);
                float sc = __expf(m - mn);
                float p  = __expf(s - mn);
                den = den * sc + p;
                acc0 = acc0 * sc + p * a.x;
                acc1 = acc1 * sc + p * a.y;
                m = mn;
            }
        }
        // merge halves (lo half has >=1 edge so no double -inf)
        float m_o  = __shfl_xor(m, 32, 64);
        float d_o  = __shfl_xor(den, 32, 64);
        float a0_o = __shfl_xor(acc0, 32, 64);
        float a1_o = __shfl_xor(acc1, 32, 64);
        float mf = fmaxf(m, m_o);
        float sc = __expf(m - mf), sco = __expf(m_o - mf);
        float denf = den * sc + d_o * sco + 1e-16f;
        float2 b = *(const float2*)(b1 + 2 * l31);
        float o0 = fmaxf((acc0 * sc + a0_o * sco) / denf + b.x, 0.f);
        float o1 = fmaxf((acc1 * sc + a1_o * sco) / denf + b.y, 0.f);
        if (half == 0) *(float2*)&sh[wid][2 * l31] = make_float2(o0, o1);
    }
    __syncthreads();
    if (node >= n) return;
    // ---- layer-2 transform: hl = h1@W2l (fp16), hr = h1@W2r (fp32), dim = lane ----
    float accl = 0.f, accr = 0.f;
#pragma unroll 8
    for (int q = 0; q < 64; ++q) {
        float hv = sh[wid][q];
        accl += hv * W2l[q * 64 + lane];
        accr += hv * W2r[q * 64 + lane];
    }
    hl[(size_t)node * 64 + lane] = __float2half(accl);
    hr[(size_t)node * 64 + lane] = accr;
}

// ---- Layer 2 fused GATv2 + pool (R10 config): wave per node, 2 edges/wave, unrolled x8.
__global__ void __launch_bounds__(256, 8)
k_gat2(const int* __restrict__ ssrc, const int* __restrict__ deg,
       const __half* __restrict__ hl, const float* __restrict__ hr,
       const float* __restrict__ att2, const float* __restrict__ b2,
       const int* __restrict__ batch,
       float* __restrict__ pooled, float* __restrict__ cnt, int n) {
    int node = __builtin_amdgcn_readfirstlane((blockIdx.x * blockDim.x + threadIdx.x) >> 6);
    if (node >= n) return;
    int lane = threadIdx.x & 63;
    int half = lane >> 5, l31 = lane & 31;
    float2 hrd  = *(const float2*)(hr + (size_t)node * 64 + 2 * l31);
    float2 attv = *(const float2*)(att2 + 2 * l31);
    float m = -INFINITY, den = 0.f, acc0 = 0.f, acc1 = 0.f;
    const int* bp_ = ssrc + (size_t)node * BUCKET;
    int end = deg[node]; if (end > BUCKET) end = BUCKET;
    int k = 0;
    for (; k + 15 < end; k += 16) {                       // 16 edges: 8 gathers in flight
        float2 a[8];
#pragma unroll
        for (int j = 0; j < 8; ++j) {
            int s0 = bp_[k + 2 * j], s1 = bp_[k + 2 * j + 1];
            int sj = half ? s1 : s0;
            a[j] = __half22float2(*(const __half2*)(hl + ((unsigned)sj << 6) + 2u * l31));
        }
        float s[8];
#pragma unroll
        for (int j = 0; j < 8; ++j)
            s[j] = lrelu(a[j].x + hrd.x) * attv.x + lrelu(a[j].y + hrd.y) * attv.y;
#pragma unroll
        for (int j = 0; j < 8; ++j) s[j] = red32(s[j]);
        float mb = fmaxf(fmaxf(fmaxf(s[0], s[1]), fmaxf(s[2], s[3])),
                         fmaxf(fmaxf(s[4], s[5]), fmaxf(s[6], s[7])));
        float mn = fmaxf(m, mb);
        float sc = __expf(m - mn);
        den *= sc; acc0 *= sc; acc1 *= sc;
#pragma unroll
        for (int j = 0; j < 8; ++j) {
            float p = __expf(s[j] - mn);
            den += p; acc0 += p * a[j].x; acc1 += p * a[j].y;
        }
        m = mn;
    }
    for (; k + 7 < end; k += 8) {                         // 8-edge tier
        float2 a[4];
#pragma unroll
        for (int j = 0; j < 4; ++j) {
            int s0 = bp_[k + 2 * j], s1 = bp_[k + 2 * j + 1];
            int sj = half ? s1 : s0;
            a[j] = __half22float2(*(const __half2*)(hl + ((unsigned)sj << 6) + 2u * l31));
        }
        float s[4];
#pragma unroll
        for (int j = 0; j < 4; ++j)
            s[j] = lrelu(a[j].x + hrd.x) * attv.x + lrelu(a[j].y + hrd.y) * attv.y;
#pragma unroll
        for (int j = 0; j < 4; ++j) s[j] = red32(s[j]);
        float mb = fmaxf(fmaxf(s[0], s[1]), fmaxf(s[2], s[3]));
        float mn = fmaxf(m, mb);
        float sc = __expf(m - mn);
        den *= sc; acc0 *= sc; acc1 *= sc;
#pragma unroll
        for (int j = 0; j < 4; ++j) {
            float p = __expf(s[j] - mn);
            den += p; acc0 += p * a[j].x; acc1 += p * a[j].y;
        }
        m = mn;
    }
    for (; k + 1 < end; k += 2) {
        int s0 = bp_[k], s1 = bp_[k + 1];
        int sj = half ? s1 : s0;
        float2 a = __half22float2(*(const __half2*)(hl + ((unsigned)sj << 6) + 2u * l31));
        float s = lrelu(a.x + hrd.x) * attv.x + lrelu(a.y + hrd.y) * attv.y;
        s = red32(s);
        float mn = fmaxf(m, s);
        float sc = __expf(m - mn);
        float p  = __expf(s - mn);
        den = den * sc + p;
        acc0 = acc0 * sc + p * a.x;
        acc1 = acc1 * sc + p * a.y;
        m = mn;
    }
    if (k < end) {                                        // odd tail: lo half only
        int sj = bp_[k];
        float2 a = __half22float2(*(const __half2*)(hl + ((unsigned)sj << 6) + 2u * l31));
        float s = lrelu(a.x + hrd.x) * attv.x + lrelu(a.y + hrd.y) * attv.y;
        s = red32(s);
        if (half == 0) {
            float mn = fmaxf(m, s);
            float sc = __expf(m - mn);
            float p  = __expf(s - mn);
            den = den * sc + p;
            acc0 = acc0 * sc + p * a.x;
            acc1 = acc1 * sc + p * a.y;
            m = mn;
        }
    }
    // merge halves
    float m_o  = __shfl_xor(m, 32, 64);
    float d_o  = __shfl_xor(den, 32, 64);
    float a0_o = __shfl_xor(acc0, 32, 64);
    float a1_o = __shfl_xor(acc1, 32, 64);
    float mf = fmaxf(m, m_o);
    float sc = __expf(m - mf), sco = __expf(m_o - mf);
    float denf = den * sc + d_o * sco + 1e-16f;
    float2 b = *(const float2*)(b2 + 2 * l31);
    float o0 = fmaxf((acc0 * sc + a0_o * sco) / denf + b.x, 0.f);
    float o1 = fmaxf((acc1 * sc + a1_o * sco) / denf + b.y, 0.f);
    // ---- pool epilogue: lane writes dim 2*l31+half (each dim exactly once) ----
    int g = batch[node];
    atomicAdd(&pooled[(size_t)g * 64 + 2 * l31 + half], half ? o1 : o0);
    if (lane == 0) atomicAdd(&cnt[g], 1.0f);
}

// ---- Predict: out[g] = dot(pooled[g]/max(cnt,1), Wp) + bp ----
__global__ void k_predict(const float* __restrict__ pooled, const float* __restrict__ cnt,
                          const float* __restrict__ Wp, const float* __restrict__ bp,
                          float* __restrict__ out, int G) {
    int tid = blockIdx.x * blockDim.x + threadIdx.x;
    int g = tid >> 6;
    if (g >= G) return;
    int lane = threadIdx.x & 63;
    float c = cnt[g];
    if (c < 1.f) c = 1.f;
    float v = (pooled[(size_t)g * 64 + lane] / c) * Wp[lane];
#pragma unroll
    for (int off = 32; off > 0; off >>= 1) v += __shfl_down(v, off, 64);
    if (lane == 0) out[g] = v + bp[0];
}

extern "C" void kernel_launch(void* const* d_in, const int* in_sizes, int n_in,
                              void* d_out, int out_size, void* d_ws, size_t ws_size,
                              hipStream_t stream) {
    const float* x    = (const float*)d_in[0];
    const int*   ei   = (const int*)d_in[1];
    const int*   batch= (const int*)d_in[2];
    const float* W1l  = (const float*)d_in[3];
    const float* W1r  = (const float*)d_in[4];
    const float* att1 = (const float*)d_in[5];
    const float* b1   = (const float*)d_in[6];
    const float* W2l  = (const float*)d_in[7];
    const float* W2r  = (const float*)d_in[8];
    const float* att2 = (const float*)d_in[9];
    const float* b2   = (const float*)d_in[10];
    const float* Wp   = (const float*)d_in[11];
    const float* bp   = (const float*)d_in[12];
    float* out = (float*)d_out;

    const int n  = in_sizes[0] / 5;        // 50000
    const int E  = in_sizes[1] / 2;        // 1600000
    const int ET = E + n;                  // +self-loops
    const int G  = out_size;               // 512

    // ---- workspace layout ----
    char* ws = (char*)d_ws;
    size_t off = 0;
    auto alloc_b = [&](size_t bytes) { void* p = (void*)(ws + off); off += (bytes + 15) & ~15ull; return p; };
    __half* xl    = (__half*)alloc_b((size_t)n * 64 * 2);  // layer-1 gather array (fp16)
    float*  xr    = (float*)alloc_b((size_t)n * 64 * 4);
    __half* hl    = (__half*)alloc_b((size_t)n * 64 * 2);  // layer-2 gather array (fp16)
    float*  hr    = (float*)alloc_b((size_t)n * 64 * 4);
    float*  pooled= (float*)alloc_b((size_t)G * 64 * 4);   // zero region start
    float*  cntf  = (float*)alloc_b((size_t)G * 4);
    int*    deg   = (int*)alloc_b((size_t)n * 4);          // zero region end
    int*    ssrc  = (int*)alloc_b((size_t)n * BUCKET * 4); // fixed-stride buckets (19.2 MB)

    size_t zero_bytes = (size_t)((char*)deg - (char*)pooled) + (size_t)n * 4;
    (void)hipMemsetAsync(pooled, 0, zero_bytes, stream);

    const int B = 256;

    // fused build: scatter (blocks 0..2047) + layer-1 transform (rest), overlapped
    const int t1_blocks = (n * 64 + B - 1) / B;
    k_build<<<8 * SC_NSUB + t1_blocks, B, 0, stream>>>(ei, deg, ssrc, E, ET, n,
                                                       x, W1l, W1r, xl, xr);

    // fused GAT layer 1 + transform2  ->  hl (fp16), hr (fp32)
    k_gat1<<<(n + 3) / 4, B, 0, stream>>>(ssrc, deg, xl, xr, att1, b1, W2l, W2r, hl, hr, n);
    // fused GAT layer 2 + pool
    k_gat2<<<((size_t)n * 64 + B - 1) / B, B, 0, stream>>>(ssrc, deg, hl, hr, att2, b2, batch, pooled, cntf, n);
    // predict
    k_predict<<<(G * 64 + B - 1) / B, B, 0, stream>>>(pooled, cntf, Wp, bp, out, G);
}

// Round 15
// 347.898 us; speedup vs baseline: 1.1562x; 1.0660x over previous
//
#include <hip/hip_runtime.h>
#include <hip/hip_fp16.h>
#include <math.h>

#define NEG_SLOPE 0.2f
#define BUCKET 96            // fixed bucket stride (slots per node); P(deg>95) ~ 1e-28

__device__ __forceinline__ float lrelu(float x) { return fmaxf(x, NEG_SLOPE * x); }

// One DPP cross-lane add step (VALU pipe, no DS ops). ctrl must be compile-time.
template <int CTRL>
__device__ __forceinline__ float dpp_add(float x) {
    int t = __builtin_amdgcn_update_dpp(0, __float_as_int(x), CTRL, 0xF, 0xF, false);
    return x + __int_as_float(t);
}

// Sum over each 8-lane group (values replicated in group).
__device__ __forceinline__ float red8(float x) {
    x = dpp_add<0xB1>(x);    // quad_perm [1,0,3,2]  (xor 1)
    x = dpp_add<0x4E>(x);    // quad_perm [2,3,0,1]  (xor 2)
    x = dpp_add<0x141>(x);   // row_half_mirror      (xor 4, quads uniform)
    return x;
}

// Sum over each 32-lane half (values replicated in half).
__device__ __forceinline__ float red32(float x) {
    x = red8(x);
    x = dpp_add<0x140>(x);           // row_mirror (xor 8, 8-groups uniform)
    x += __shfl_xor(x, 16, 64);      // xor 16 (stays within each 32-half)
    return x;
}

// ---- CSR build, one pass: dst-range-partitioned direct scatter into fixed buckets.
// partition == blockIdx%8 (XCD-local if round-robin holds) -> bucket writes stay
// in one XCD's L2; src read only for in-range edges.
__global__ void k_scatter(const int* __restrict__ ei, int* __restrict__ cnt,
                          int* __restrict__ ssrc, int E, int ET, int n, int nsub) {
    int part = blockIdx.x & 7;
    int sub  = blockIdx.x >> 3;
    int lo = (int)(((long long)part * n) >> 3);
    int hi = (int)(((long long)(part + 1) * n) >> 3);
    int stride = nsub * blockDim.x;
    for (int e = sub * blockDim.x + threadIdx.x; e < ET; e += stride) {
        int dst = (e < E) ? ei[E + e] : (e - E);
        if (dst >= lo && dst < hi) {
            int src = (e < E) ? ei[e] : dst;
            int pos = atomicAdd(&cnt[dst], 1);
            if (pos < BUCKET) ssrc[dst * BUCKET + pos] = src;
        }
    }
}

// ---- Layer-1 node transform: xl1 = x@W1l (fp16), xr1 = x@W1r (fp32) ----
__global__ void k_t1(const float* __restrict__ x,
                     const float* __restrict__ W1l, const float* __restrict__ W1r,
                     __half* __restrict__ xl, float* __restrict__ xr, int n) {
    __shared__ float sWl[5 * 64], sWr[5 * 64];
    int t = threadIdx.x;
    for (int i = t; i < 5 * 64; i += blockDim.x) { sWl[i] = W1l[i]; sWr[i] = W1r[i]; }
    __syncthreads();
    int tid = blockIdx.x * blockDim.x + t;
    if (tid >= n * 64) return;
    int node = tid >> 6, j = tid & 63;
    const float* xp = x + node * 5;
    float x0 = xp[0], x1 = xp[1], x2 = xp[2], x3 = xp[3], x4 = xp[4];
    float al = x0 * sWl[j] + x1 * sWl[64 + j] + x2 * sWl[128 + j] + x3 * sWl[192 + j] + x4 * sWl[256 + j];
    float ar = x0 * sWr[j] + x1 * sWr[64 + j] + x2 * sWr[128 + j] + x3 * sWr[192 + j] + x4 * sWr[256 + j];
    xl[tid] = __float2half(al);
    xr[tid] = ar;
}

// ---- Layer 1 fused GATv2 (R10 config): wave per node, 2 edges/wave (32 lanes x 2 dims),
//      unrolled x8 (16 edges, 8 gathers/lane in flight). Head logit = 8-lane DPP.
//      Epilogue: h1 -> LDS -> layer-2 transform (hl fp16, hr fp32).
//      NOTE (R11-R14): every perturbation of this loop regressed — keep as is.
__global__ void __launch_bounds__(256, 8)
k_gat1(const int* __restrict__ ssrc, const int* __restrict__ deg,
       const __half* __restrict__ xl, const float* __restrict__ xr,
       const float* __restrict__ att1, const float* __restrict__ b1,
       const float* __restrict__ W2l, const float* __restrict__ W2r,
       __half* __restrict__ hl, float* __restrict__ hr, int n) {
    __shared__ float sh[4][64];
    int t = threadIdx.x;
    int wid = t >> 6, lane = t & 63;
    int node = __builtin_amdgcn_readfirstlane(blockIdx.x * 4 + wid);
    int half = lane >> 5, l31 = lane & 31;
    if (node < n) {
        float2 xrd  = *(const float2*)(xr + (size_t)node * 64 + 2 * l31);
        float2 attv = *(const float2*)(att1 + 2 * l31);
        float m = -INFINITY, den = 0.f, acc0 = 0.f, acc1 = 0.f;
        const int* bp_ = ssrc + (size_t)node * BUCKET;    // bucket base (node uniform)
        int end = deg[node]; if (end > BUCKET) end = BUCKET;
        int k = 0;
        for (; k + 15 < end; k += 16) {                   // 16 edges: 8 gathers in flight
            float2 a[8];
#pragma unroll
            for (int j = 0; j < 8; ++j) {
                int s0 = bp_[k + 2 * j], s1 = bp_[k + 2 * j + 1];
                int sj = half ? s1 : s0;
                a[j] = __half22float2(*(const __half2*)(xl + ((unsigned)sj << 6) + 2u * l31));
            }
            float s[8];
#pragma unroll
            for (int j = 0; j < 8; ++j)
                s[j] = lrelu(a[j].x + xrd.x) * attv.x + lrelu(a[j].y + xrd.y) * attv.y;
#pragma unroll
            for (int j = 0; j < 8; ++j) s[j] = red8(s[j]);
            float mb = fmaxf(fmaxf(fmaxf(s[0], s[1]), fmaxf(s[2], s[3])),
                             fmaxf(fmaxf(s[4], s[5]), fmaxf(s[6], s[7])));
            float mn = fmaxf(m, mb);
            float sc = __expf(m - mn);
            den *= sc; acc0 *= sc; acc1 *= sc;
#pragma unroll
            for (int j = 0; j < 8; ++j) {
                float p = __expf(s[j] - mn);
                den += p; acc0 += p * a[j].x; acc1 += p * a[j].y;
            }
            m = mn;
        }
        for (; k + 7 < end; k += 8) {                     // 8-edge tier
            float2 a[4];
#pragma unroll
            for (int j = 0; j < 4; ++j) {
                int s0 = bp_[k + 2 * j], s1 = bp_[k + 2 * j + 1];
                int sj = half ? s1 : s0;
                a[j] = __half22float2(*(const __half2*)(xl + ((unsigned)sj << 6) + 2u * l31));
            }
            float s[4];
#pragma unroll
            for (int j = 0; j < 4; ++j)
                s[j] = lrelu(a[j].x + xrd.x) * attv.x + lrelu(a[j].y + xrd.y) * attv.y;
#pragma unroll
            for (int j = 0; j < 4; ++j) s[j] = red8(s[j]);
            float mb = fmaxf(fmaxf(s[0], s[1]), fmaxf(s[2], s[3]));
            float mn = fmaxf(m, mb);
            float sc = __expf(m - mn);
            den *= sc; acc0 *= sc; acc1 *= sc;
#pragma unroll
            for (int j = 0; j < 4; ++j) {
                float p = __expf(s[j] - mn);
                den += p; acc0 += p * a[j].x; acc1 += p * a[j].y;
            }
            m = mn;
        }
        for (; k + 1 < end; k += 2) {
            int s0 = bp_[k], s1 = bp_[k + 1];
            int sj = half ? s1 : s0;
            float2 a = __half22float2(*(const __half2*)(xl + ((unsigned)sj << 6) + 2u * l31));
            float s = lrelu(a.x + xrd.x) * attv.x + lrelu(a.y + xrd.y) * attv.y;
            s = red8(s);
            float mn = fmaxf(m, s);
            float sc = __expf(m - mn);
            float p  = __expf(s - mn);
            den = den * sc + p;
            acc0 = acc0 * sc + p * a.x;
            acc1 = acc1 * sc + p * a.y;
            m = mn;
        }
        if (k < end) {                                    // odd tail: lo half only
            int sj = bp_[k];
            float2 a = __half22float2(*(const __half2*)(xl + ((unsigned)sj << 6) + 2u * l31));
            float s = lrelu(a.x + xrd.x) * attv.x + lrelu(a.y + xrd.y) * attv.y;
            s = red8(s);
            if (half == 0) {
                float mn = fmaxf(m, s);
                float sc = __expf(m - mn);
                float p  = __expf(s - mn);
                den = den * sc + p;
                acc0 = acc0 * sc + p * a.x;
                acc1 = acc1 * sc + p * a.y;
                m = mn;
            }
        }
        // merge halves (lo half has >=1 edge so no double -inf)
        float m_o  = __shfl_xor(m, 32, 64);
        float d_o  = __shfl_xor(den, 32, 64);
        float a0_o = __shfl_xor(acc0, 32, 64);
        float a1_o = __shfl_xor(acc1, 32, 64);
        float mf = fmaxf(m, m_o);
        float sc = __expf(m - mf), sco = __expf(m_o - mf);
        float denf = den * sc + d_o * sco + 1e-16f;
        float2 b = *(const float2*)(b1 + 2 * l31);
        float o0 = fmaxf((acc0 * sc + a0_o * sco) / denf + b.x, 0.f);
        float o1 = fmaxf((acc1 * sc + a1_o * sco) / denf + b.y, 0.f);
        if (half == 0) *(float2*)&sh[wid][2 * l31] = make_float2(o0, o1);
    }
    __syncthreads();
    if (node >= n) return;
    // ---- layer-2 transform: hl = h1@W2l (fp16), hr = h1@W2r (fp32), dim = lane ----
    float accl = 0.f, accr = 0.f;
#pragma unroll 8
    for (int q = 0; q < 64; ++q) {
        float hv = sh[wid][q];
        accl += hv * W2l[q * 64 + lane];
        accr += hv * W2r[q * 64 + lane];
    }
    hl[(size_t)node * 64 + lane] = __float2half(accl);
    hr[(size_t)node * 64 + lane] = accr;
}

// ---- Layer 2 fused GATv2 + pool (R10 config): wave per node, 2 edges/wave, unrolled x8.
__global__ void __launch_bounds__(256, 8)
k_gat2(const int* __restrict__ ssrc, const int* __restrict__ deg,
       const __half* __restrict__ hl, const float* __restrict__ hr,
       const float* __restrict__ att2, const float* __restrict__ b2,
       const int* __restrict__ batch,
       float* __restrict__ pooled, float* __restrict__ cnt, int n) {
    int node = __builtin_amdgcn_readfirstlane((blockIdx.x * blockDim.x + threadIdx.x) >> 6);
    if (node >= n) return;
    int lane = threadIdx.x & 63;
    int half = lane >> 5, l31 = lane & 31;
    float2 hrd  = *(const float2*)(hr + (size_t)node * 64 + 2 * l31);
    float2 attv = *(const float2*)(att2 + 2 * l31);
    float m = -INFINITY, den = 0.f, acc0 = 0.f, acc1 = 0.f;
    const int* bp_ = ssrc + (size_t)node * BUCKET;
    int end = deg[node]; if (end > BUCKET) end = BUCKET;
    int k = 0;
    for (; k + 15 < end; k += 16) {                       // 16 edges: 8 gathers in flight
        float2 a[8];
#pragma unroll
        for (int j = 0; j < 8; ++j) {
            int s0 = bp_[k + 2 * j], s1 = bp_[k + 2 * j + 1];
            int sj = half ? s1 : s0;
            a[j] = __half22float2(*(const __half2*)(hl + ((unsigned)sj << 6) + 2u * l31));
        }
        float s[8];
#pragma unroll
        for (int j = 0; j < 8; ++j)
            s[j] = lrelu(a[j].x + hrd.x) * attv.x + lrelu(a[j].y + hrd.y) * attv.y;
#pragma unroll
        for (int j = 0; j < 8; ++j) s[j] = red32(s[j]);
        float mb = fmaxf(fmaxf(fmaxf(s[0], s[1]), fmaxf(s[2], s[3])),
                         fmaxf(fmaxf(s[4], s[5]), fmaxf(s[6], s[7])));
        float mn = fmaxf(m, mb);
        float sc = __expf(m - mn);
        den *= sc; acc0 *= sc; acc1 *= sc;
#pragma unroll
        for (int j = 0; j < 8; ++j) {
            float p = __expf(s[j] - mn);
            den += p; acc0 += p * a[j].x; acc1 += p * a[j].y;
        }
        m = mn;
    }
    for (; k + 7 < end; k += 8) {                         // 8-edge tier
        float2 a[4];
#pragma unroll
        for (int j = 0; j < 4; ++j) {
            int s0 = bp_[k + 2 * j], s1 = bp_[k + 2 * j + 1];
            int sj = half ? s1 : s0;
            a[j] = __half22float2(*(const __half2*)(hl + ((unsigned)sj << 6) + 2u * l31));
        }
        float s[4];
#pragma unroll
        for (int j = 0; j < 4; ++j)
            s[j] = lrelu(a[j].x + hrd.x) * attv.x + lrelu(a[j].y + hrd.y) * attv.y;
#pragma unroll
        for (int j = 0; j < 4; ++j) s[j] = red32(s[j]);
        float mb = fmaxf(fmaxf(s[0], s[1]), fmaxf(s[2], s[3]));
        float mn = fmaxf(m, mb);
        float sc = __expf(m - mn);
        den *= sc; acc0 *= sc; acc1 *= sc;
#pragma unroll
        for (int j = 0; j < 4; ++j) {
            float p = __expf(s[j] - mn);
            den += p; acc0 += p * a[j].x; acc1 += p * a[j].y;
        }
        m = mn;
    }
    for (; k + 1 < end; k += 2) {
        int s0 = bp_[k], s1 = bp_[k + 1];
        int sj = half ? s1 : s0;
        float2 a = __half22float2(*(const __half2*)(hl + ((unsigned)sj << 6) + 2u * l31));
        float s = lrelu(a.x + hrd.x) * attv.x + lrelu(a.y + hrd.y) * attv.y;
        s = red32(s);
        float mn = fmaxf(m, s);
        float sc = __expf(m - mn);
        float p  = __expf(s - mn);
        den = den * sc + p;
        acc0 = acc0 * sc + p * a.x;
        acc1 = acc1 * sc + p * a.y;
        m = mn;
    }
    if (k < end) {                                        // odd tail: lo half only
        int sj = bp_[k];
        float2 a = __half22float2(*(const __half2*)(hl + ((unsigned)sj << 6) + 2u * l31));
        float s = lrelu(a.x + hrd.x) * attv.x + lrelu(a.y + hrd.y) * attv.y;
        s = red32(s);
        if (half == 0) {
            float mn = fmaxf(m, s);
            float sc = __expf(m - mn);
            float p  = __expf(s - mn);
            den = den * sc + p;
            acc0 = acc0 * sc + p * a.x;
            acc1 = acc1 * sc + p * a.y;
            m = mn;
        }
    }
    // merge halves
    float m_o  = __shfl_xor(m, 32, 64);
    float d_o  = __shfl_xor(den, 32, 64);
    float a0_o = __shfl_xor(acc0, 32, 64);
    float a1_o = __shfl_xor(acc1, 32, 64);
    float mf = fmaxf(m, m_o);
    float sc = __expf(m - mf), sco = __expf(m_o - mf);
    float denf = den * sc + d_o * sco + 1e-16f;
    float2 b = *(const float2*)(b2 + 2 * l31);
    float o0 = fmaxf((acc0 * sc + a0_o * sco) / denf + b.x, 0.f);
    float o1 = fmaxf((acc1 * sc + a1_o * sco) / denf + b.y, 0.f);
    // ---- pool epilogue: lane writes dim 2*l31+half (each dim exactly once) ----
    int g = batch[node];
    atomicAdd(&pooled[(size_t)g * 64 + 2 * l31 + half], half ? o1 : o0);
    if (lane == 0) atomicAdd(&cnt[g], 1.0f);
}

// ---- Predict: out[g] = dot(pooled[g]/max(cnt,1), Wp) + bp ----
__global__ void k_predict(const float* __restrict__ pooled, const float* __restrict__ cnt,
                          const float* __restrict__ Wp, const float* __restrict__ bp,
                          float* __restrict__ out, int G) {
    int tid = blockIdx.x * blockDim.x + threadIdx.x;
    int g = tid >> 6;
    if (g >= G) return;
    int lane = threadIdx.x & 63;
    float c = cnt[g];
    if (c < 1.f) c = 1.f;
    float v = (pooled[(size_t)g * 64 + lane] / c) * Wp[lane];
#pragma unroll
    for (int off = 32; off > 0; off >>= 1) v += __shfl_down(v, off, 64);
    if (lane == 0) out[g] = v + bp[0];
}

extern "C" void kernel_launch(void* const* d_in, const int* in_sizes, int n_in,
                              void* d_out, int out_size, void* d_ws, size_t ws_size,
                              hipStream_t stream) {
    const float* x    = (const float*)d_in[0];
    const int*   ei   = (const int*)d_in[1];
    const int*   batch= (const int*)d_in[2];
    const float* W1l  = (const float*)d_in[3];
    const float* W1r  = (const float*)d_in[4];
    const float* att1 = (const float*)d_in[5];
    const float* b1   = (const float*)d_in[6];
    const float* W2l  = (const float*)d_in[7];
    const float* W2r  = (const float*)d_in[8];
    const float* att2 = (const float*)d_in[9];
    const float* b2   = (const float*)d_in[10];
    const float* Wp   = (const float*)d_in[11];
    const float* bp   = (const float*)d_in[12];
    float* out = (float*)d_out;

    const int n  = in_sizes[0] / 5;        // 50000
    const int E  = in_sizes[1] / 2;        // 1600000
    const int ET = E + n;                  // +self-loops
    const int G  = out_size;               // 512

    // ---- workspace layout ----
    char* ws = (char*)d_ws;
    size_t off = 0;
    auto alloc_b = [&](size_t bytes) { void* p = (void*)(ws + off); off += (bytes + 15) & ~15ull; return p; };
    __half* xl    = (__half*)alloc_b((size_t)n * 64 * 2);  // layer-1 gather array (fp16)
    float*  xr    = (float*)alloc_b((size_t)n * 64 * 4);
    __half* hl    = (__half*)alloc_b((size_t)n * 64 * 2);  // layer-2 gather array (fp16)
    float*  hr    = (float*)alloc_b((size_t)n * 64 * 4);
    float*  pooled= (float*)alloc_b((size_t)G * 64 * 4);   // zero region start
    float*  cntf  = (float*)alloc_b((size_t)G * 4);
    int*    deg   = (int*)alloc_b((size_t)n * 4);          // zero region end
    int*    ssrc  = (int*)alloc_b((size_t)n * BUCKET * 4); // fixed-stride buckets (19.2 MB)

    size_t zero_bytes = (size_t)((char*)deg - (char*)pooled) + (size_t)n * 4;
    (void)hipMemsetAsync(pooled, 0, zero_bytes, stream);

    const int B = 256;
    const int NSUB = 256;                  // edge-chunks per dst-partition

    // one-pass CSR build into fixed buckets (deg[] = degrees as byproduct)
    k_scatter<<<8 * NSUB, B, 0, stream>>>(ei, deg, ssrc, E, ET, n, NSUB);

    // layer-1 node transform
    k_t1<<<(n * 64 + B - 1) / B, B, 0, stream>>>(x, W1l, W1r, xl, xr, n);

    // fused GAT layer 1 + transform2  ->  hl (fp16), hr (fp32)
    k_gat1<<<(n + 3) / 4, B, 0, stream>>>(ssrc, deg, xl, xr, att1, b1, W2l, W2r, hl, hr, n);
    // fused GAT layer 2 + pool
    k_gat2<<<((size_t)n * 64 + B - 1) / B, B, 0, stream>>>(ssrc, deg, hl, hr, att2, b2, batch, pooled, cntf, n);
    // predict
    k_predict<<<(G * 64 + B - 1) / B, B, 0, stream>>>(pooled, cntf, Wp, bp, out, G);
}